// Round 1
// baseline (25.678 us; speedup 1.0000x reference)
//
#include <hip/hip_runtime.h>

// z[i] = w * ( b * sum_t a^(T-1-t) x[i,t] + c * (1-a^T)/(1-a) ) + e
// T = 8192, B = 4096, x row-major [B][T], fp32.

constexpr int T_LEN = 8192;
constexpr int BLOCK = 256;
constexpr int CHUNKS = T_LEN / (BLOCK * 4);  // 8 float4 chunks per thread

__global__ __launch_bounds__(BLOCK) void recur_row_kernel(
    const float* __restrict__ x,
    const float* __restrict__ pa, const float* __restrict__ pb,
    const float* __restrict__ pc, const float* __restrict__ pw,
    const float* __restrict__ pe, float* __restrict__ out)
{
    const int row = blockIdx.x;
    const int j = threadIdx.x;

    const float a = pa[0];
    const float b = pb[0];
    const float c = pc[0];
    const float w = pw[0];
    const float e = pe[0];

    // Exact-ish powers via double binary exponentiation (once per thread).
    const double ad = (double)a;
    double a1024d = ad;
    #pragma unroll
    for (int i = 0; i < 10; ++i) a1024d *= a1024d;   // a^1024
    const float A1024 = (float)a1024d;

    // per-thread combine weight: a^(4*(255-j))
    int expn = 4 * (BLOCK - 1 - j);
    double wgt_d = 1.0, base = ad;
    while (expn) { if (expn & 1) wgt_d *= base; base *= base; expn >>= 1; }
    const float wgt = (float)wgt_d;

    // Each thread: chunks u=0..7, float4 at element offset u*1024 + 4*j.
    const float4* xr = reinterpret_cast<const float4*>(x + (size_t)row * T_LEN);
    float p = 0.0f;
    #pragma unroll
    for (int u = 0; u < CHUNKS; ++u) {
        float4 v = xr[u * BLOCK + j];
        float q = ((v.x * a + v.y) * a + v.z) * a + v.w;  // Horner over 4 elems
        p = A1024 * p + q;                                 // combine chunks
    }
    float part = wgt * p;

    // 64-lane wave reduce, then cross-wave via LDS.
    #pragma unroll
    for (int off = 32; off > 0; off >>= 1)
        part += __shfl_down(part, off, 64);

    __shared__ float sred[BLOCK / 64];
    const int lane = j & 63, wid = j >> 6;
    if (lane == 0) sred[wid] = part;
    __syncthreads();

    if (j == 0) {
        float D = sred[0] + sred[1] + sred[2] + sred[3];
        // S = sum_{k=0}^{T-1} a^k = (1 - a^T) / (1 - a), in double.
        double a8192 = a1024d * a1024d;   // a^2048
        a8192 *= a8192;                   // a^4096
        a8192 *= a8192;                   // a^8192
        double S = (1.0 - a8192) / (1.0 - ad);
        out[row] = w * (b * D + c * (float)S) + e;
    }
}

extern "C" void kernel_launch(void* const* d_in, const int* in_sizes, int n_in,
                              void* d_out, int out_size, void* d_ws, size_t ws_size,
                              hipStream_t stream) {
    const float* x  = (const float*)d_in[0];
    const float* pa = (const float*)d_in[1];
    const float* pb = (const float*)d_in[2];
    const float* pc = (const float*)d_in[3];
    const float* pw = (const float*)d_in[4];
    const float* pe = (const float*)d_in[5];
    float* out = (float*)d_out;

    const int B = out_size;  // 4096 rows
    recur_row_kernel<<<dim3(B), dim3(BLOCK), 0, stream>>>(x, pa, pb, pc, pw, pe, out);
}

// Round 3
// 24.485 us; speedup vs baseline: 1.0487x; 1.0487x over previous
//
#include <hip/hip_runtime.h>

// z[i] = w * ( b * sum_t a^(T-1-t) x[i,t] + c * (1-a^T)/(1-a) ) + e
// T = 8192, B = 4096, x row-major [B][T], fp32.
// One 64-lane wave per row; 256-thread block = 4 rows; grid = B/4 = 1024.

constexpr int T_LEN = 8192;
constexpr int BLOCK = 256;
constexpr int ROWS_PER_BLOCK = BLOCK / 64;          // 4
constexpr int CHUNKS = T_LEN / (64 * 4);            // 32 float4 chunks per lane

typedef float vfloat4 __attribute__((ext_vector_type(4)));  // native vec for nontemporal builtin

__global__ __launch_bounds__(BLOCK) void recur_row_kernel(
    const float* __restrict__ x,
    const float* __restrict__ pa, const float* __restrict__ pb,
    const float* __restrict__ pc, const float* __restrict__ pw,
    const float* __restrict__ pe, float* __restrict__ out)
{
    const int wid  = threadIdx.x >> 6;              // wave id in block: 0..3
    const int lane = threadIdx.x & 63;
    const int row  = blockIdx.x * ROWS_PER_BLOCK + wid;

    const float a = pa[0];
    const float b = pb[0];
    const float c = pc[0];
    const float w = pw[0];
    const float e = pe[0];

    // Double-precision powers (once per thread; negligible vs 32 KB stream).
    const double ad = (double)a;
    double a256d = ad;
    #pragma unroll
    for (int i = 0; i < 8; ++i) a256d *= a256d;     // a^256
    const float A256 = (float)a256d;

    // Per-lane combine weight: a^(4*(63-lane))
    int expn = 4 * (63 - lane);
    double wgt_d = 1.0, base = ad;
    while (expn) { if (expn & 1) wgt_d *= base; base *= base; expn >>= 1; }
    const float wgt = (float)wgt_d;

    // Stream the row: lane reads float4 at u*64 + lane, u = 0..31.
    const vfloat4* xr = reinterpret_cast<const vfloat4*>(x + (size_t)row * T_LEN);
    float p = 0.0f;
    #pragma unroll
    for (int u = 0; u < CHUNKS; ++u) {
        vfloat4 v = __builtin_nontemporal_load(&xr[u * 64 + lane]);
        float q = ((v.x * a + v.y) * a + v.z) * a + v.w;   // Horner over 4 elems
        p = A256 * p + q;                                   // combine chunks
    }
    float part = wgt * p;

    // 64-lane wave reduce; no LDS, no barrier.
    #pragma unroll
    for (int off = 32; off > 0; off >>= 1)
        part += __shfl_down(part, off, 64);

    if (lane == 0) {
        // S = (1 - a^T) / (1 - a), in double.
        double a8192 = a256d * a256d;    // a^512
        a8192 *= a8192;                  // a^1024
        a8192 *= a8192;                  // a^2048
        a8192 *= a8192;                  // a^4096
        a8192 *= a8192;                  // a^8192
        double S = (1.0 - a8192) / (1.0 - ad);
        out[row] = w * (b * part + c * (float)S) + e;
    }
}

extern "C" void kernel_launch(void* const* d_in, const int* in_sizes, int n_in,
                              void* d_out, int out_size, void* d_ws, size_t ws_size,
                              hipStream_t stream) {
    const float* x  = (const float*)d_in[0];
    const float* pa = (const float*)d_in[1];
    const float* pb = (const float*)d_in[2];
    const float* pc = (const float*)d_in[3];
    const float* pw = (const float*)d_in[4];
    const float* pe = (const float*)d_in[5];
    float* out = (float*)d_out;

    const int B = out_size;  // 4096 rows
    recur_row_kernel<<<dim3(B / ROWS_PER_BLOCK), dim3(BLOCK), 0, stream>>>(
        x, pa, pb, pc, pw, pe, out);
}